// Round 1
// baseline (524.472 us; speedup 1.0000x reference)
//
#include <hip/hip_runtime.h>
#include <hip/hip_bf16.h>

#define NVV    40962
#define NVP    10242
#define BB     8
#define CIN    64
#define COUT   64
#define KK     7
#define NGROUP 32
#define EPSV   1e-5f

// d_ws layout: stats[b*64 + 2*g + 0] = sum, [.. + 1] = sumsq   (8*64 floats = 2 KB)

__global__ __launch_bounds__(256, 2) void k_conv(
    const float* __restrict__ x,
    const float* __restrict__ Lw,
    const float* __restrict__ Ew,
    const float* __restrict__ Nw,
    const float* __restrict__ coeffs,
    const float* __restrict__ bias,
    const int*   __restrict__ nbr,
    float* __restrict__ out,
    float* __restrict__ stats)
{
    const int bid   = blockIdx.x;
    const int b     = bid & (BB - 1);          // b <-> XCD affinity for L2 locality on x[b]
    const int vbase = (bid >> 3) << 8;
    const int tid   = threadIdx.x;
    const int v     = vbase + tid;
    const bool active = (v < NVV);

    float acc[COUT];
    #pragma unroll
    for (int o = 0; o < COUT; ++o) acc[o] = bias[o];

    int   jj[KK];
    float wl[KK], we[KK], wn[KK];
    #pragma unroll
    for (int k = 0; k < KK; ++k) { jj[k] = NVP; wl[k] = 0.f; we[k] = 0.f; wn[k] = 0.f; }
    if (active) {
        #pragma unroll
        for (int k = 0; k < KK; ++k) {
            jj[k] = nbr[v * KK + k];
            wl[k] = Lw[v * KK + k];
            we[k] = Ew[v * KK + k];
            wn[k] = Nw[v * KK + k];
        }
    }

    const float* xb = x + (size_t)b * CIN * NVP;

    #pragma unroll 1
    for (int i0 = 0; i0 < CIN; i0 += 4) {
        float fu[4], fl[4], fe[4], fn[4];
        #pragma unroll
        for (int ii = 0; ii < 4; ++ii) {
            const float* xc = xb + (size_t)(i0 + ii) * NVP;
            float u = 0.f;
            if (v < NVP) u = xc[v];
            float l = 0.f, e = 0.f, n = 0.f;
            #pragma unroll
            for (int k = 0; k < KK; ++k) {
                float g = 0.f;
                int j = jj[k];
                if (j < NVP) g = xc[j];     // 75% of gathers exec-masked off (zero pad)
                l = fmaf(g, wl[k], l);
                e = fmaf(g, we[k], e);
                n = fmaf(g, wn[k], n);
            }
            fu[ii] = u; fl[ii] = l; fe[ii] = e; fn[ii] = n;
        }
        // coeffs[(o*64 + i0)*4 .. +16) is 16 contiguous floats, wave-uniform address
        const float* cbase = coeffs + i0 * 4;
        #pragma unroll
        for (int o = 0; o < COUT; ++o) {       // full unroll: acc[] must stay in VGPRs
            const float* c = cbase + o * (CIN * 4);
            float a = acc[o];
            #pragma unroll
            for (int ii = 0; ii < 4; ++ii) {
                a = fmaf(c[ii * 4 + 0], fu[ii], a);
                a = fmaf(c[ii * 4 + 1], fl[ii], a);
                a = fmaf(c[ii * 4 + 2], fe[ii], a);
                a = fmaf(c[ii * 4 + 3], fn[ii], a);
            }
            acc[o] = a;
        }
    }

    if (active) {
        float* ob = out + (size_t)b * COUT * NVV + v;
        #pragma unroll
        for (int o = 0; o < COUT; ++o) ob[(size_t)o * NVV] = acc[o];
    }

    // GroupNorm partial stats: per group g = {2g, 2g+1}, wave shuffle-reduce -> LDS -> atomics
    __shared__ float red[4][64];
    const int wave = tid >> 6;
    const int lane = tid & 63;
    #pragma unroll
    for (int g = 0; g < NGROUP; ++g) {
        float a0 = active ? acc[2 * g]     : 0.f;
        float a1 = active ? acc[2 * g + 1] : 0.f;
        float s  = a0 + a1;
        float s2 = a0 * a0 + a1 * a1;
        #pragma unroll
        for (int off = 32; off > 0; off >>= 1) {
            s  += __shfl_down(s,  off);
            s2 += __shfl_down(s2, off);
        }
        if (lane == 0) { red[wave][2 * g] = s; red[wave][2 * g + 1] = s2; }
    }
    __syncthreads();
    if (tid < 64) {
        float r = red[0][tid] + red[1][tid] + red[2][tid] + red[3][tid];
        atomicAdd(&stats[b * 64 + tid], r);
    }
}

__global__ __launch_bounds__(256) void k_norm(
    float* __restrict__ out,
    const float* __restrict__ stats,
    const float* __restrict__ gamma,
    const float* __restrict__ beta)
{
    unsigned int p = blockIdx.x * 256u + threadIdx.x;   // grid covers exactly B*COUT*NVV/2
    unsigned int n = p * 2u;
    unsigned int row = n / NVV;            // = b*64 + o  (pairs never cross rows: NVV even)
    unsigned int o = row & (COUT - 1);
    unsigned int b = row >> 6;
    unsigned int g = o >> 1;
    const float inv_cnt = 1.f / (float)(2 * NVV);
    float sum  = stats[b * 64 + 2 * g];
    float ssq  = stats[b * 64 + 2 * g + 1];
    float mean = sum * inv_cnt;
    float var  = fmaf(ssq, inv_cnt, -mean * mean);
    float rs   = rsqrtf(var + EPSV);
    float sc   = gamma[o] * rs;
    float sh   = fmaf(-mean, sc, beta[o]);
    float2 val = *(const float2*)(out + n);
    float y0 = fmaf(val.x, sc, sh);
    float y1 = fmaf(val.y, sc, sh);
    val.x = y0 > 0.f ? y0 : 0.f;
    val.y = y1 > 0.f ? y1 : 0.f;
    *(float2*)(out + n) = val;
}

extern "C" void kernel_launch(void* const* d_in, const int* in_sizes, int n_in,
                              void* d_out, int out_size, void* d_ws, size_t ws_size,
                              hipStream_t stream) {
    const float* x      = (const float*)d_in[0];
    const float* Lw     = (const float*)d_in[1];
    const float* Ew     = (const float*)d_in[2];
    const float* Nw     = (const float*)d_in[3];
    const float* coeffs = (const float*)d_in[4];
    const float* bias   = (const float*)d_in[5];
    const float* gamma  = (const float*)d_in[6];
    const float* beta   = (const float*)d_in[7];
    const int*   nbr    = (const int*)d_in[8];
    float* out   = (float*)d_out;
    float* stats = (float*)d_ws;

    hipMemsetAsync(stats, 0, BB * 64 * sizeof(float), stream);  // ws is re-poisoned 0xAA each call

    const int vtiles = (NVV + 255) / 256;                       // 161
    k_conv<<<dim3(BB * vtiles), dim3(256), 0, stream>>>(x, Lw, Ew, Nw, coeffs, bias, nbr, out, stats);

    const unsigned int total2 = (unsigned int)BB * COUT * NVV / 2;  // 10,486,272
    k_norm<<<dim3(total2 / 256), dim3(256), 0, stream>>>(out, stats, gamma, beta);
}

// Round 2
// 471.870 us; speedup vs baseline: 1.1115x; 1.1115x over previous
//
#include <hip/hip_runtime.h>
#include <hip/hip_bf16.h>

#define NVV    40962
#define NVP    10242
#define BB     8
#define CIN    64
#define COUT   64
#define KK     7
#define NGROUP 32
#define EPSV   1e-5f

// d_ws layout: stats[b*64 + 2*g + 0] = sum, [.. + 1] = sumsq   (8*64 floats = 2 KB)

__device__ __forceinline__ float2 pkfma(float2 a, float2 b, float2 c) {
    return make_float2(fmaf(a.x, b.x, c.x), fmaf(a.y, b.y, c.y));
}

__global__ __launch_bounds__(256) void k_conv(
    const float* __restrict__ x,
    const float* __restrict__ Lw,
    const float* __restrict__ Ew,
    const float* __restrict__ Nw,
    const float* __restrict__ coeffs,
    const float* __restrict__ bias,
    const int*   __restrict__ nbr,
    float* __restrict__ out,
    float* __restrict__ stats)
{
    const int bid   = blockIdx.x;
    const int b     = bid & (BB - 1);          // b <-> XCD affinity for L2 locality on x[b]
    const int vbase = (bid >> 3) << 8;
    const int tid   = threadIdx.x;
    const int v     = vbase + tid;
    const bool active = (v < NVV);

    // packed accumulators: acc[o2] = {C[2*o2], C[2*o2+1]}  -> target v_pk_fma_f32
    float2 acc[COUT / 2];
    #pragma unroll
    for (int o2 = 0; o2 < COUT / 2; ++o2)
        acc[o2] = make_float2(bias[2 * o2], bias[2 * o2 + 1]);

    int   jj[KK];
    float wl[KK], we[KK], wn[KK];
    #pragma unroll
    for (int k = 0; k < KK; ++k) { jj[k] = NVP; wl[k] = 0.f; we[k] = 0.f; wn[k] = 0.f; }
    if (active) {
        #pragma unroll
        for (int k = 0; k < KK; ++k) {
            jj[k] = nbr[v * KK + k];
            wl[k] = Lw[v * KK + k];
            we[k] = Ew[v * KK + k];
            wn[k] = Nw[v * KK + k];
        }
    }

    const float* xb = x + (size_t)b * CIN * NVP;

    #pragma unroll 1
    for (int i0 = 0; i0 < CIN; i0 += 4) {
        float fu[4], fl[4], fe[4], fn[4];
        #pragma unroll
        for (int ii = 0; ii < 4; ++ii) {
            const float* xc = xb + (size_t)(i0 + ii) * NVP;
            float u = 0.f;
            if (v < NVP) u = xc[v];
            float l = 0.f, e = 0.f, n = 0.f;
            #pragma unroll
            for (int k = 0; k < KK; ++k) {
                float g = 0.f;
                int j = jj[k];
                if (j < NVP) g = xc[j];     // ~75% of gathers exec-masked off (zero pad)
                l = fmaf(g, wl[k], l);
                e = fmaf(g, we[k], e);
                n = fmaf(g, wn[k], n);
            }
            fu[ii] = u; fl[ii] = l; fe[ii] = e; fn[ii] = n;
        }
        // coeffs[(o*64 + i0)*4 .. +16) : 16 contiguous floats per o, wave-uniform (SGPR)
        const float* cbase = coeffs + i0 * 4;
        #pragma unroll
        for (int o2 = 0; o2 < COUT / 2; ++o2) {
            const float* cA = cbase + (2 * o2) * (CIN * 4);
            const float* cB = cA + (CIN * 4);
            float2 a = acc[o2];
            #pragma unroll
            for (int ii = 0; ii < 4; ++ii) {
                a = pkfma(make_float2(cA[ii * 4 + 0], cB[ii * 4 + 0]), make_float2(fu[ii], fu[ii]), a);
                a = pkfma(make_float2(cA[ii * 4 + 1], cB[ii * 4 + 1]), make_float2(fl[ii], fl[ii]), a);
                a = pkfma(make_float2(cA[ii * 4 + 2], cB[ii * 4 + 2]), make_float2(fe[ii], fe[ii]), a);
                a = pkfma(make_float2(cA[ii * 4 + 3], cB[ii * 4 + 3]), make_float2(fn[ii], fn[ii]), a);
            }
            acc[o2] = a;
        }
    }

    if (active) {
        float* ob = out + (size_t)b * COUT * NVV + v;
        #pragma unroll
        for (int o2 = 0; o2 < COUT / 2; ++o2) {
            ob[(size_t)(2 * o2) * NVV]     = acc[o2].x;
            ob[(size_t)(2 * o2 + 1) * NVV] = acc[o2].y;
        }
    }

    // GroupNorm partial stats: group g covers channels {2g,2g+1} = acc[g].{x,y}
    __shared__ float red[4][64];
    const int wave = tid >> 6;
    const int lane = tid & 63;
    #pragma unroll
    for (int g = 0; g < NGROUP; ++g) {
        float a0 = active ? acc[g].x : 0.f;
        float a1 = active ? acc[g].y : 0.f;
        float s  = a0 + a1;
        float s2 = fmaf(a0, a0, a1 * a1);
        #pragma unroll
        for (int off = 32; off > 0; off >>= 1) {
            s  += __shfl_down(s,  off);
            s2 += __shfl_down(s2, off);
        }
        if (lane == 0) { red[wave][2 * g] = s; red[wave][2 * g + 1] = s2; }
    }
    __syncthreads();
    if (tid < 64) {
        float r = red[0][tid] + red[1][tid] + red[2][tid] + red[3][tid];
        atomicAdd(&stats[b * 64 + tid], r);
    }
}

// grid: (ceil((NVV/2)/256), B*COUT). Row-uniform stats -> scalar path, no int divide.
__global__ __launch_bounds__(256) void k_norm(
    float* __restrict__ out,
    const float* __restrict__ stats,
    const float* __restrict__ gamma,
    const float* __restrict__ beta)
{
    const int row = blockIdx.y;            // = b*64 + o
    const int o = row & (COUT - 1);
    const int b = row >> 6;
    const int g = o >> 1;
    const float inv_cnt = 1.f / (float)(2 * NVV);
    float sum  = stats[b * 64 + 2 * g];
    float ssq  = stats[b * 64 + 2 * g + 1];
    float mean = sum * inv_cnt;
    float var  = fmaf(ssq, inv_cnt, -mean * mean);
    float rs   = rsqrtf(var + EPSV);
    float sc   = gamma[o] * rs;
    float sh   = fmaf(-mean, sc, beta[o]);

    const int c = blockIdx.x * 256 + threadIdx.x;      // float2 index within row
    if (c < NVV / 2) {
        float* p = out + (size_t)row * NVV + 2 * c;
        float2 val = *(const float2*)p;
        float y0 = fmaf(val.x, sc, sh);
        float y1 = fmaf(val.y, sc, sh);
        val.x = y0 > 0.f ? y0 : 0.f;
        val.y = y1 > 0.f ? y1 : 0.f;
        *(float2*)p = val;
    }
}

extern "C" void kernel_launch(void* const* d_in, const int* in_sizes, int n_in,
                              void* d_out, int out_size, void* d_ws, size_t ws_size,
                              hipStream_t stream) {
    const float* x      = (const float*)d_in[0];
    const float* Lw     = (const float*)d_in[1];
    const float* Ew     = (const float*)d_in[2];
    const float* Nw     = (const float*)d_in[3];
    const float* coeffs = (const float*)d_in[4];
    const float* bias   = (const float*)d_in[5];
    const float* gamma  = (const float*)d_in[6];
    const float* beta   = (const float*)d_in[7];
    const int*   nbr    = (const int*)d_in[8];
    float* out   = (float*)d_out;
    float* stats = (float*)d_ws;

    hipMemsetAsync(stats, 0, BB * 64 * sizeof(float), stream);  // ws is re-poisoned 0xAA each call

    const int vtiles = (NVV + 255) / 256;                       // 161
    k_conv<<<dim3(BB * vtiles), dim3(256), 0, stream>>>(x, Lw, Ew, Nw, coeffs, bias, nbr, out, stats);

    const int cols2 = (NVV / 2 + 255) / 256;                    // 81
    k_norm<<<dim3(cols2, BB * COUT), dim3(256), 0, stream>>>(out, stats, gamma, beta);
}

// Round 4
// 295.467 us; speedup vs baseline: 1.7751x; 1.5970x over previous
//
#include <hip/hip_runtime.h>
#include <hip/hip_bf16.h>

#define NVV    40962
#define NVP    10242
#define BB     8
#define CIN    64
#define COUT   64
#define KK     7
#define EPSV   1e-5f

#define VT     64            // vertices per tile
#define NTILE  641           // ceil(NVV/VT)
#define KDIM   256           // Cin*4
#define ROWS   264           // padded LDS row (bf16 elems): 528 B, 16B-aligned, stride≡4 mod 32 banks

typedef __attribute__((ext_vector_type(8))) short short8;
typedef __attribute__((ext_vector_type(4))) float floatx4;

__device__ __forceinline__ unsigned short f2bf(float f) {
    unsigned u = __builtin_bit_cast(unsigned, f);
    return (unsigned short)((u + 0x7FFFu + ((u >> 16) & 1u)) >> 16);  // rne (finite inputs)
}

// d_ws: stats[b*64 + 2*g + {0,1}] = {sum, sumsq}  (8*64 floats = 2 KB)

__global__ __launch_bounds__(256, 1) void k_conv(
    const float* __restrict__ x,
    const float* __restrict__ Lw,
    const float* __restrict__ Ew,
    const float* __restrict__ Nw,
    const float* __restrict__ coeffs,
    const float* __restrict__ bias,
    const int*   __restrict__ nbr,
    float* __restrict__ out,
    float* __restrict__ stats)
{
    __shared__ unsigned short F[VT * ROWS];   // F[v][k] bf16, k = i*4 + f
    __shared__ float sred[4][4][4];

    const int bid   = blockIdx.x;
    const int b     = bid & 7;                // b <-> XCD affinity: x[b] slab (2.6MB) L2-resident
    const int tile  = bid >> 3;
    const int vbase = tile * VT;
    const int tid   = threadIdx.x;
    const int wave  = tid >> 6;
    const int lane  = tid & 63;
    const int q     = lane >> 4;              // quad
    const int l15   = lane & 15;

    // ---- W fragments, resident in VGPRs for the whole block ----
    // A-operand of mfma_16x16x32_bf16: lane holds A[m=l15][k = 32*k0 + 8*q + j], j=0..7
    short8 afrag[8];
    {
        const float* wrow = coeffs + (16 * wave + l15) * KDIM + q * 8;
        #pragma unroll
        for (int k0 = 0; k0 < 8; ++k0) {
            const float* wp = wrow + k0 * 32;
            short8 s;
            #pragma unroll
            for (int j = 0; j < 8; ++j) s[j] = (short)f2bf(wp[j]);
            afrag[k0] = s;
        }
    }

    // ---- Stage A: build feat tile in LDS (bf16) ----
    {
        const int v  = tid & 63;              // local v; threads v-major so jj coalesced
        const int vg = vbase + v;
        const int ic = tid >> 6;              // i in [16*ic, 16*ic+16)
        const bool va = (vg < NVV);
        int jj[KK]; float wl[KK], we[KK], wn[KK];
        #pragma unroll
        for (int k = 0; k < KK; ++k) { jj[k] = NVP; wl[k] = we[k] = wn[k] = 0.f; }
        if (va) {
            #pragma unroll
            for (int k = 0; k < KK; ++k) {
                jj[k] = nbr[vg * KK + k];
                wl[k] = Lw[vg * KK + k];
                we[k] = Ew[vg * KK + k];
                wn[k] = Nw[vg * KK + k];
            }
        }
        const bool up_ok = (vg < NVP);
        const float* xb = x + (size_t)b * CIN * NVP;
        unsigned short* Fv = F + v * ROWS;
        #pragma unroll 2
        for (int t = 0; t < 16; ++t) {
            const int i = ic * 16 + t;
            const float* xc = xb + (size_t)i * NVP;
            float u = up_ok ? xc[vg] : 0.f;
            float l = 0.f, e = 0.f, n = 0.f;
            #pragma unroll
            for (int k = 0; k < KK; ++k) {
                float g = 0.f;
                if (jj[k] < NVP) g = xc[jj[k]];   // ~75% masked off (zero pad region)
                l = fmaf(g, wl[k], l);
                e = fmaf(g, we[k], e);
                n = fmaf(g, wn[k], n);
            }
            unsigned p0 = (unsigned)f2bf(u) | ((unsigned)f2bf(l) << 16);
            unsigned p1 = (unsigned)f2bf(e) | ((unsigned)f2bf(n) << 16);
            *(uint2*)(Fv + i * 4) = make_uint2(p0, p1);   // ds_write_b64, k=4i..4i+3
        }
    }
    __syncthreads();

    // ---- Stage B: 4 waves x 16-o strips; B-frag: B[n=l15][k=32*k0+8*q+j] from F ----
    floatx4 acc[4] = {{0,0,0,0},{0,0,0,0},{0,0,0,0},{0,0,0,0}};
    #pragma unroll
    for (int k0 = 0; k0 < 8; ++k0) {
        #pragma unroll
        for (int nt = 0; nt < 4; ++nt) {
            const short8 bfrag = *(const short8*)(F + (nt * 16 + l15) * ROWS + k0 * 32 + q * 8);
            acc[nt] = __builtin_amdgcn_mfma_f32_16x16x32_bf16(afrag[k0], bfrag, acc[nt], 0, 0, 0);
        }
    }

    // ---- Epilogue: bias, store, GN partial stats ----
    // C/D layout: col = l15 = v-within-ntile, row = q*4 + r = o-within-strip
    float bs[4];
    #pragma unroll
    for (int r = 0; r < 4; ++r) bs[r] = bias[16 * wave + q * 4 + r];

    float sA = 0.f, s2A = 0.f, sB = 0.f, s2B = 0.f;
    float* ob = out + ((size_t)b * COUT + 16 * wave + q * 4) * NVV + vbase + l15;
    #pragma unroll
    for (int nt = 0; nt < 4; ++nt) {
        const int vg = vbase + nt * 16 + l15;
        const bool ok = (vg < NVV);
        #pragma unroll
        for (int r = 0; r < 4; ++r) {
            float c = acc[nt][r] + bs[r];
            if (ok) {
                ob[(size_t)r * NVV + nt * 16] = c;
                if (r < 2) { sA += c; s2A = fmaf(c, c, s2A); }
                else       { sB += c; s2B = fmaf(c, c, s2B); }
            }
        }
    }
    // reduce over the 16 lanes sharing q (v dimension)
    #pragma unroll
    for (int m = 1; m < 16; m <<= 1) {
        sA  += __shfl_xor(sA,  m);
        s2A += __shfl_xor(s2A, m);
        sB  += __shfl_xor(sB,  m);
        s2B += __shfl_xor(s2B, m);
    }
    if (l15 == 0) {
        sred[wave][q][0] = sA; sred[wave][q][1] = s2A;
        sred[wave][q][2] = sB; sred[wave][q][3] = s2B;
    }
    __syncthreads();
    if (tid < 64) {
        const int w = tid >> 4, qq = (tid >> 2) & 3, e = tid & 3;
        const int g = 8 * w + 2 * qq + (e >> 1);     // o-pair {2g,2g+1}
        atomicAdd(&stats[b * 64 + 2 * g + (e & 1)], sred[w][qq][e]);
    }
}

// grid: (81, B*COUT); row-uniform stats -> scalar path. NVV is EVEN: the float2
// sweep over c < NVV/2 covers every element exactly once (no tail handling!).
__global__ __launch_bounds__(256) void k_norm(
    float* __restrict__ out,
    const float* __restrict__ stats,
    const float* __restrict__ gamma,
    const float* __restrict__ beta)
{
    const int row = blockIdx.y;                 // b*64 + o
    const int o = row & (COUT - 1);
    const int b = row >> 6;
    const int g = o >> 1;
    const float inv_cnt = 1.f / (float)(2 * NVV);
    const float mean = stats[b * 64 + 2 * g] * inv_cnt;
    const float var  = fmaf(stats[b * 64 + 2 * g + 1], inv_cnt, -mean * mean);
    const float rs   = rsqrtf(var + EPSV);
    const float sc   = gamma[o] * rs;
    const float sh   = fmaf(-mean, sc, beta[o]);

    const int c = blockIdx.x * 256 + threadIdx.x;   // float2 index within row
    if (c < NVV / 2) {
        float* p = out + (size_t)row * NVV + 2 * c;
        float2 val = *(const float2*)p;
        float y0 = fmaf(val.x, sc, sh);
        float y1 = fmaf(val.y, sc, sh);
        val.x = y0 > 0.f ? y0 : 0.f;
        val.y = y1 > 0.f ? y1 : 0.f;
        *(float2*)p = val;
    }
}

extern "C" void kernel_launch(void* const* d_in, const int* in_sizes, int n_in,
                              void* d_out, int out_size, void* d_ws, size_t ws_size,
                              hipStream_t stream) {
    const float* x      = (const float*)d_in[0];
    const float* Lw     = (const float*)d_in[1];
    const float* Ew     = (const float*)d_in[2];
    const float* Nw     = (const float*)d_in[3];
    const float* coeffs = (const float*)d_in[4];
    const float* bias   = (const float*)d_in[5];
    const float* gamma  = (const float*)d_in[6];
    const float* beta   = (const float*)d_in[7];
    const int*   nbr    = (const int*)d_in[8];
    float* out   = (float*)d_out;
    float* stats = (float*)d_ws;

    hipMemsetAsync(stats, 0, BB * 64 * sizeof(float), stream);

    k_conv<<<dim3(BB * NTILE), dim3(256), 0, stream>>>(x, Lw, Ew, Nw, coeffs, bias, nbr, out, stats);

    const int cols2 = (NVV / 2 + 255) / 256;   // 81
    k_norm<<<dim3(cols2, BB * COUT), dim3(256), 0, stream>>>(out, stats, gamma, beta);
}

// Round 5
// 221.055 us; speedup vs baseline: 2.3726x; 1.3366x over previous
//
#include <hip/hip_runtime.h>
#include <hip/hip_bf16.h>

#define NVV    40962
#define NVP    10242
#define BB     8
#define CIN    64
#define COUT   64
#define KK     7
#define EPSV   1e-5f

#define VT     64            // vertices per tile
#define NTILE  641           // ceil(NVV/VT)
#define KDIM   256           // Cin*4

typedef __attribute__((ext_vector_type(8))) short short8;
typedef __attribute__((ext_vector_type(4))) float floatx4;

__device__ __forceinline__ unsigned f2bf(float f) {
    unsigned u = __builtin_bit_cast(unsigned, f);
    return (u + 0x7FFFu + ((u >> 16) & 1u)) >> 16;    // rne (finite inputs)
}

// d_ws: [0,2KB) stats: stats[b*64 + 2*g + {0,1}] = {sum,sumsq}
//       [2KB, 2KB + 8*10242*64*4) xT[b][v][i]  (~21 MB)

// ---- transpose x[b][i][v] -> xT[b][v][i], LDS 64x64 tiles ----
__global__ __launch_bounds__(256) void k_tr(const float* __restrict__ x,
                                            float* __restrict__ xT) {
    __shared__ float tile[64][65];
    const int b    = blockIdx.y;
    const int v0   = blockIdx.x * 64;
    const int lane = threadIdx.x & 63;
    const int wave = threadIdx.x >> 6;
    const int v    = v0 + lane;
    #pragma unroll
    for (int r = 0; r < 16; ++r) {
        int i = wave * 16 + r;
        tile[i][lane] = (v < NVP) ? x[((size_t)b * CIN + i) * NVP + v] : 0.f;
    }
    __syncthreads();
    #pragma unroll
    for (int r = 0; r < 16; ++r) {
        int vv = wave * 16 + r;
        if (v0 + vv < NVP)
            xT[((size_t)b * NVP + v0 + vv) * 64 + lane] = tile[lane][vv];
    }
}

__global__ __launch_bounds__(256, 4) void k_conv(
    const float* __restrict__ xT,
    const float* __restrict__ Lw,
    const float* __restrict__ Ew,
    const float* __restrict__ Nw,
    const float* __restrict__ coeffs,
    const float* __restrict__ bias,
    const int*   __restrict__ nbr,
    float* __restrict__ out,
    float* __restrict__ stats)
{
    // F: 64 rows x 256 bf16 (512 B/row), XOR-swizzled in 16B groups:
    //   phys_group = group ^ (row & 31)  -> conflict-free writes AND frag reads
    __shared__ unsigned short Fbuf[VT * 256];       // 32 KB; reused as float outT[64][68]
    __shared__ float sred[4][4][4];

    const int bid   = blockIdx.x;
    const int b     = bid & 7;                // b <-> XCD affinity: xT[b] slab (2.6MB) L2-resident
    const int tile  = bid >> 3;
    const int vbase = tile * VT;
    const int tid   = threadIdx.x;
    const int wave  = tid >> 6;
    const int lane  = tid & 63;
    const int q     = lane >> 4;
    const int l15   = lane & 15;

    // ---- Stage A: thread (v=lane, i-range = wave*16..+16); coalesced xT rows ----
    {
        const int v  = lane;
        const int ic = wave;
        const int vg = vbase + v;
        const bool va = (vg < NVV);
        int jj[KK]; float wl[KK], we[KK], wn[KK];
        #pragma unroll
        for (int k = 0; k < KK; ++k) { jj[k] = NVP; wl[k] = we[k] = wn[k] = 0.f; }
        if (va) {
            #pragma unroll
            for (int k = 0; k < KK; ++k) {
                jj[k] = nbr[vg * KK + k];
                wl[k] = Lw[vg * KK + k];
                we[k] = Ew[vg * KK + k];
                wn[k] = Nw[vg * KK + k];
            }
        }
        const float* xTb = xT + (size_t)b * NVP * 64 + ic * 16;
        float u[16], l[16], e[16], n[16];
        #pragma unroll
        for (int t = 0; t < 16; ++t) { u[t] = l[t] = e[t] = n[t] = 0.f; }
        if (vg < NVP) {
            const float* p = xTb + (size_t)vg * 64;
            #pragma unroll
            for (int s = 0; s < 4; ++s) {
                float4 t = *(const float4*)(p + 4 * s);
                u[4*s] = t.x; u[4*s+1] = t.y; u[4*s+2] = t.z; u[4*s+3] = t.w;
            }
        }
        #pragma unroll
        for (int k = 0; k < KK; ++k) {
            const int j = jj[k];
            if (j < NVP) {                      // ~25% lanes active; full 256B row reuse
                const float* p = xTb + (size_t)j * 64;
                const float a = wl[k], bb2 = we[k], c2 = wn[k];
                #pragma unroll
                for (int s = 0; s < 4; ++s) {
                    float4 t = *(const float4*)(p + 4 * s);
                    l[4*s]   = fmaf(t.x, a, l[4*s]);   e[4*s]   = fmaf(t.x, bb2, e[4*s]);   n[4*s]   = fmaf(t.x, c2, n[4*s]);
                    l[4*s+1] = fmaf(t.y, a, l[4*s+1]); e[4*s+1] = fmaf(t.y, bb2, e[4*s+1]); n[4*s+1] = fmaf(t.y, c2, n[4*s+1]);
                    l[4*s+2] = fmaf(t.z, a, l[4*s+2]); e[4*s+2] = fmaf(t.z, bb2, e[4*s+2]); n[4*s+2] = fmaf(t.z, c2, n[4*s+2]);
                    l[4*s+3] = fmaf(t.w, a, l[4*s+3]); e[4*s+3] = fmaf(t.w, bb2, e[4*s+3]); n[4*s+3] = fmaf(t.w, c2, n[4*s+3]);
                }
            }
        }
        // pack: group g holds k=8g..8g+7 = i-pair {2g,2g+1} x {u,l,e,n}
        #pragma unroll
        for (int jg = 0; jg < 8; ++jg) {
            const int i0 = 2 * jg;             // local i within this wave's 16
            uint4 w;
            w.x = f2bf(u[i0])   | (f2bf(l[i0])   << 16);
            w.y = f2bf(e[i0])   | (f2bf(n[i0])   << 16);
            w.z = f2bf(u[i0+1]) | (f2bf(l[i0+1]) << 16);
            w.w = f2bf(e[i0+1]) | (f2bf(n[i0+1]) << 16);
            const int g    = ic * 8 + jg;
            const int phys = g ^ (v & 31);
            *(uint4*)(Fbuf + v * 256 + phys * 8) = w;
        }
    }
    __syncthreads();

    // ---- W fragments (A-operand): lane holds A[m=l15][k=32*k0+8*q+j] ----
    short8 afrag[8];
    {
        const float* wrow = coeffs + (16 * wave + l15) * KDIM + q * 8;
        #pragma unroll
        for (int k0 = 0; k0 < 8; ++k0) {
            const float* wp = wrow + k0 * 32;
            short8 s;
            #pragma unroll
            for (int j = 0; j < 8; ++j) s[j] = (short)f2bf(wp[j]);
            afrag[k0] = s;
        }
    }

    // ---- MFMA: B[n=l15][k] from swizzled F ----
    floatx4 acc[4] = {{0,0,0,0},{0,0,0,0},{0,0,0,0},{0,0,0,0}};
    #pragma unroll
    for (int k0 = 0; k0 < 8; ++k0) {
        #pragma unroll
        for (int nt = 0; nt < 4; ++nt) {
            const int row  = nt * 16 + l15;
            const int phys = (k0 * 4 + q) ^ (row & 31);
            const short8 bfrag = *(const short8*)(Fbuf + row * 256 + phys * 8);
            acc[nt] = __builtin_amdgcn_mfma_f32_16x16x32_bf16(afrag[k0], bfrag, acc[nt], 0, 0, 0);
        }
    }

    // ---- Epilogue: bias, GN partial stats, LDS-transposed coalesced stores ----
    // C/D layout: col=l15 (v within nt), row=q*4+r (o within 16-strip)
    float bs[4];
    #pragma unroll
    for (int r = 0; r < 4; ++r) bs[r] = bias[16 * wave + q * 4 + r];

    float cv[4][4];
    float sA = 0.f, s2A = 0.f, sB = 0.f, s2B = 0.f;
    #pragma unroll
    for (int nt = 0; nt < 4; ++nt) {
        const bool ok = (vbase + nt * 16 + l15 < NVV);
        #pragma unroll
        for (int r = 0; r < 4; ++r) {
            float c = acc[nt][r] + bs[r];
            cv[nt][r] = c;
            if (ok) {
                if (r < 2) { sA += c; s2A = fmaf(c, c, s2A); }
                else       { sB += c; s2B = fmaf(c, c, s2B); }
            }
        }
    }
    #pragma unroll
    for (int m = 1; m < 16; m <<= 1) {
        sA  += __shfl_xor(sA,  m);
        s2A += __shfl_xor(s2A, m);
        sB  += __shfl_xor(sB,  m);
        s2B += __shfl_xor(s2B, m);
    }
    if (l15 == 0) {
        sred[wave][q][0] = sA; sred[wave][q][1] = s2A;
        sred[wave][q][2] = sB; sred[wave][q][3] = s2B;
    }
    __syncthreads();                 // F reads done; safe to reuse Fbuf as outT

    float* outT = (float*)Fbuf;      // [64 o][stride 68] floats = 17.4 KB
    #pragma unroll
    for (int nt = 0; nt < 4; ++nt)
        #pragma unroll
        for (int r = 0; r < 4; ++r)
            outT[(16 * wave + 4 * q + r) * 68 + nt * 16 + l15] = cv[nt][r];
    __syncthreads();

    const bool okS = (vbase + lane < NVV);
    float* ob = out + ((size_t)b * COUT + 16 * wave) * NVV + vbase + lane;
    #pragma unroll
    for (int oo = 0; oo < 16; ++oo) {
        float val = outT[(16 * wave + oo) * 68 + lane];
        if (okS) ob[(size_t)oo * NVV] = val;    // 256 B/wave-inst contiguous
    }

    if (tid < 64) {
        const int w = tid >> 4, qq = (tid >> 2) & 3, e = tid & 3;
        const int g = 8 * w + 2 * qq + (e >> 1);
        atomicAdd(&stats[b * 64 + 2 * g + (e & 1)], sred[w][qq][e]);
    }
}

// grid: (81, B*COUT); row-uniform stats -> scalar path. NVV even: float2 sweep exact.
__global__ __launch_bounds__(256) void k_norm(
    float* __restrict__ out,
    const float* __restrict__ stats,
    const float* __restrict__ gamma,
    const float* __restrict__ beta)
{
    const int row = blockIdx.y;                 // b*64 + o
    const int o = row & (COUT - 1);
    const int b = row >> 6;
    const int g = o >> 1;
    const float inv_cnt = 1.f / (float)(2 * NVV);
    const float mean = stats[b * 64 + 2 * g] * inv_cnt;
    const float var  = fmaf(stats[b * 64 + 2 * g + 1], inv_cnt, -mean * mean);
    const float rs   = rsqrtf(var + EPSV);
    const float sc   = gamma[o] * rs;
    const float sh   = fmaf(-mean, sc, beta[o]);

    const int c = blockIdx.x * 256 + threadIdx.x;
    if (c < NVV / 2) {
        float* p = out + (size_t)row * NVV + 2 * c;
        float2 val = *(const float2*)p;
        float y0 = fmaf(val.x, sc, sh);
        float y1 = fmaf(val.y, sc, sh);
        val.x = y0 > 0.f ? y0 : 0.f;
        val.y = y1 > 0.f ? y1 : 0.f;
        *(float2*)p = val;
    }
}

extern "C" void kernel_launch(void* const* d_in, const int* in_sizes, int n_in,
                              void* d_out, int out_size, void* d_ws, size_t ws_size,
                              hipStream_t stream) {
    const float* x      = (const float*)d_in[0];
    const float* Lw     = (const float*)d_in[1];
    const float* Ew     = (const float*)d_in[2];
    const float* Nw     = (const float*)d_in[3];
    const float* coeffs = (const float*)d_in[4];
    const float* bias   = (const float*)d_in[5];
    const float* gamma  = (const float*)d_in[6];
    const float* beta   = (const float*)d_in[7];
    const int*   nbr    = (const int*)d_in[8];
    float* out   = (float*)d_out;
    float* stats = (float*)d_ws;
    float* xT    = (float*)((char*)d_ws + 2048);   // needs ws_size >= ~21 MB

    hipMemsetAsync(stats, 0, BB * 64 * sizeof(float), stream);

    k_tr<<<dim3(161, BB), dim3(256), 0, stream>>>(x, xT);

    k_conv<<<dim3(BB * NTILE), dim3(256), 0, stream>>>(xT, Lw, Ew, Nw, coeffs, bias, nbr, out, stats);

    const int cols2 = (NVV / 2 + 255) / 256;   // 81
    k_norm<<<dim3(cols2, BB * COUT), dim3(256), 0, stream>>>(out, stats, gamma, beta);
}

// Round 7
// 213.216 us; speedup vs baseline: 2.4598x; 1.0368x over previous
//
#include <hip/hip_runtime.h>
#include <hip/hip_bf16.h>

#define NVV    40962
#define NVP    10242
#define BB     8
#define CIN    64
#define COUT   64
#define KK     7
#define EPSV   1e-5f

#define VT     64            // vertices per tile
#define NTILE  641           // ceil(NVV/VT)
#define KDIM   256           // Cin*4

typedef __attribute__((ext_vector_type(8))) short short8;
typedef __attribute__((ext_vector_type(4))) float floatx4;

__device__ __forceinline__ unsigned f2bf(float f) {
    unsigned u = __builtin_bit_cast(unsigned, f);
    return (u + 0x7FFFu + ((u >> 16) & 1u)) >> 16;    // rne (finite inputs)
}
__device__ __forceinline__ unsigned pk2(float a, float b) {   // v_cvt_pk_bf16_f32
    __hip_bfloat162 h = __float22bfloat162_rn(make_float2(a, b));
    unsigned r;
    __builtin_memcpy(&r, &h, 4);                       // bit_cast rejects non-trivial type
    return r;
}

// d_ws: [0, 2KB)           stats[b*64 + 2*g + {0,1}] = {sum,sumsq}
//       [2KB, 2KB+32KB)    cW[o][k] bf16 coeffs (64x256)
//       [36864, +21MB)     xT[b][v][i] f32

// ---- one-shot: coeffs f32 -> bf16 row-major ----
__global__ __launch_bounds__(256) void k_prep(const float* __restrict__ coeffs,
                                              unsigned short* __restrict__ cW) {
    for (int t = threadIdx.x; t < COUT * KDIM; t += 256)
        cW[t] = (unsigned short)f2bf(coeffs[t]);
}

// ---- transpose x[b][i][v] -> xT[b][v][i], LDS 64x64 tiles ----
__global__ __launch_bounds__(256) void k_tr(const float* __restrict__ x,
                                            float* __restrict__ xT) {
    __shared__ float tile[64][65];
    const int b    = blockIdx.y;
    const int v0   = blockIdx.x * 64;
    const int lane = threadIdx.x & 63;
    const int wave = threadIdx.x >> 6;
    const int v    = v0 + lane;
    #pragma unroll
    for (int r = 0; r < 16; ++r) {
        int i = wave * 16 + r;
        tile[i][lane] = (v < NVP) ? x[((size_t)b * CIN + i) * NVP + v] : 0.f;
    }
    __syncthreads();
    #pragma unroll
    for (int r = 0; r < 16; ++r) {
        int vv = wave * 16 + r;
        if (v0 + vv < NVP)
            xT[((size_t)b * NVP + v0 + vv) * 64 + lane] = tile[lane][vv];
    }
}

__global__ __launch_bounds__(256, 4) void k_conv(
    const float* __restrict__ xT,
    const float* __restrict__ Lw,
    const float* __restrict__ Ew,
    const float* __restrict__ Nw,
    const unsigned short* __restrict__ cW,
    const float* __restrict__ bias,
    const int*   __restrict__ nbr,
    float* __restrict__ out,
    float* __restrict__ stats)
{
    // F: 64 rows x 256 bf16 (512 B/row), XOR-swizzled in 16B groups:
    //   phys_group = group ^ (row & 31)  -> conflict-free writes AND frag reads
    __shared__ unsigned short Fbuf[VT * 256];       // 32 KB; reused as float outT[64][68]
    __shared__ float sred[4][4][4];

    const int bid   = blockIdx.x;
    const int b     = bid & 7;                // b <-> XCD affinity: xT[b] slab (2.6MB) L2-resident
    const int tile  = bid >> 3;
    const int vbase = tile * VT;
    const int tid   = threadIdx.x;
    const int wave  = tid >> 6;
    const int lane  = tid & 63;
    const int q     = lane >> 4;
    const int l15   = lane & 15;

    // ---- Stage A: thread (v=lane, i-range = wave*16..+16); coalesced xT rows ----
    {
        const int v  = lane;
        const int ic = wave;
        const int vg = vbase + v;
        const bool va = (vg < NVV);
        int jj[KK]; float wl[KK], we[KK], wn[KK];
        #pragma unroll
        for (int k = 0; k < KK; ++k) { jj[k] = NVP; wl[k] = we[k] = wn[k] = 0.f; }
        if (va) {
            #pragma unroll
            for (int k = 0; k < KK; ++k) {
                jj[k] = nbr[vg * KK + k];
                wl[k] = Lw[vg * KK + k];
                we[k] = Ew[vg * KK + k];
                wn[k] = Nw[vg * KK + k];
            }
        }
        const float* xTb = xT + (size_t)b * NVP * 64 + ic * 16;
        float u[16], l[16], e[16], n[16];
        #pragma unroll
        for (int t = 0; t < 16; ++t) { u[t] = l[t] = e[t] = n[t] = 0.f; }
        if (vg < NVP) {
            const float* p = xTb + (size_t)vg * 64;
            #pragma unroll
            for (int s = 0; s < 4; ++s) {
                float4 t = *(const float4*)(p + 4 * s);
                u[4*s] = t.x; u[4*s+1] = t.y; u[4*s+2] = t.z; u[4*s+3] = t.w;
            }
        }
        #pragma unroll
        for (int k = 0; k < KK; ++k) {
            const int j = jj[k];
            if (j < NVP) {                      // ~25% lanes active; full 256B row reuse
                const float* p = xTb + (size_t)j * 64;
                const float a = wl[k], bb2 = we[k], c2 = wn[k];
                #pragma unroll
                for (int s = 0; s < 4; ++s) {
                    float4 t = *(const float4*)(p + 4 * s);
                    l[4*s]   = fmaf(t.x, a, l[4*s]);   e[4*s]   = fmaf(t.x, bb2, e[4*s]);   n[4*s]   = fmaf(t.x, c2, n[4*s]);
                    l[4*s+1] = fmaf(t.y, a, l[4*s+1]); e[4*s+1] = fmaf(t.y, bb2, e[4*s+1]); n[4*s+1] = fmaf(t.y, c2, n[4*s+1]);
                    l[4*s+2] = fmaf(t.z, a, l[4*s+2]); e[4*s+2] = fmaf(t.z, bb2, e[4*s+2]); n[4*s+2] = fmaf(t.z, c2, n[4*s+2]);
                    l[4*s+3] = fmaf(t.w, a, l[4*s+3]); e[4*s+3] = fmaf(t.w, bb2, e[4*s+3]); n[4*s+3] = fmaf(t.w, c2, n[4*s+3]);
                }
            }
        }
        // pack: group g holds k=8g..8g+7 = i-pair {2g,2g+1} x {u,l,e,n}
        #pragma unroll
        for (int jg = 0; jg < 8; ++jg) {
            const int i0 = 2 * jg;             // local i within this wave's 16
            uint4 w;
            w.x = pk2(u[i0],   l[i0]);
            w.y = pk2(e[i0],   n[i0]);
            w.z = pk2(u[i0+1], l[i0+1]);
            w.w = pk2(e[i0+1], n[i0+1]);
            const int g    = ic * 8 + jg;
            const int phys = g ^ (v & 31);
            *(uint4*)(Fbuf + v * 256 + phys * 8) = w;
        }
    }
    __syncthreads();

    // ---- W fragments (A-operand): lane holds A[m=l15][k=32*k0+8*q+j]; direct bf16 load ----
    short8 afrag[8];
    {
        const unsigned short* wrow = cW + (16 * wave + l15) * KDIM + q * 8;
        #pragma unroll
        for (int k0 = 0; k0 < 8; ++k0)
            afrag[k0] = *(const short8*)(wrow + k0 * 32);   // 16B aligned
    }

    // ---- MFMA: B[n=l15][k] from swizzled F ----
    floatx4 acc[4] = {{0,0,0,0},{0,0,0,0},{0,0,0,0},{0,0,0,0}};
    #pragma unroll
    for (int k0 = 0; k0 < 8; ++k0) {
        #pragma unroll
        for (int nt = 0; nt < 4; ++nt) {
            const int row  = nt * 16 + l15;
            const int phys = (k0 * 4 + q) ^ (row & 31);
            const short8 bfrag = *(const short8*)(Fbuf + row * 256 + phys * 8);
            acc[nt] = __builtin_amdgcn_mfma_f32_16x16x32_bf16(afrag[k0], bfrag, acc[nt], 0, 0, 0);
        }
    }

    // ---- Epilogue: bias, GN partial stats, LDS-transposed coalesced stores ----
    // C/D layout: col=l15 (v within nt), row=q*4+r (o within 16-strip)
    float bs[4];
    #pragma unroll
    for (int r = 0; r < 4; ++r) bs[r] = bias[16 * wave + q * 4 + r];

    float cv[4][4];
    float sA = 0.f, s2A = 0.f, sB = 0.f, s2B = 0.f;
    #pragma unroll
    for (int nt = 0; nt < 4; ++nt) {
        const bool ok = (vbase + nt * 16 + l15 < NVV);
        #pragma unroll
        for (int r = 0; r < 4; ++r) {
            float c = acc[nt][r] + bs[r];
            cv[nt][r] = c;
            if (ok) {
                if (r < 2) { sA += c; s2A = fmaf(c, c, s2A); }
                else       { sB += c; s2B = fmaf(c, c, s2B); }
            }
        }
    }
    #pragma unroll
    for (int m = 1; m < 16; m <<= 1) {
        sA  += __shfl_xor(sA,  m);
        s2A += __shfl_xor(s2A, m);
        sB  += __shfl_xor(sB,  m);
        s2B += __shfl_xor(s2B, m);
    }
    if (l15 == 0) {
        sred[wave][q][0] = sA; sred[wave][q][1] = s2A;
        sred[wave][q][2] = sB; sred[wave][q][3] = s2B;
    }
    __syncthreads();                 // F reads done; safe to reuse Fbuf as outT

    float* outT = (float*)Fbuf;      // [64 o][stride 68] floats = 17.4 KB
    #pragma unroll
    for (int nt = 0; nt < 4; ++nt)
        #pragma unroll
        for (int r = 0; r < 4; ++r)
            outT[(16 * wave + 4 * q + r) * 68 + nt * 16 + l15] = cv[nt][r];
    __syncthreads();

    const bool okS = (vbase + lane < NVV);
    float* ob = out + ((size_t)b * COUT + 16 * wave) * NVV + vbase + lane;
    #pragma unroll
    for (int oo = 0; oo < 16; ++oo) {
        float val = outT[(16 * wave + oo) * 68 + lane];
        if (okS) ob[(size_t)oo * NVV] = val;    // 256 B/wave-inst contiguous
    }

    if (tid < 64) {
        const int w = tid >> 4, qq = (tid >> 2) & 3, e = tid & 3;
        const int g = 8 * w + 2 * qq + (e >> 1);
        atomicAdd(&stats[b * 64 + 2 * g + (e & 1)], sred[w][qq][e]);
    }
}

// grid: 1024 blocks = 2 per row; each thread strides float2 over its half-row.
__global__ __launch_bounds__(256) void k_norm(
    float* __restrict__ out,
    const float* __restrict__ stats,
    const float* __restrict__ gamma,
    const float* __restrict__ beta)
{
    const int row  = blockIdx.x >> 1;           // b*64 + o
    const int half = blockIdx.x & 1;
    const int o = row & (COUT - 1);
    const int b = row >> 6;
    const int g = o >> 1;
    const float inv_cnt = 1.f / (float)(2 * NVV);
    const float mean = stats[b * 64 + 2 * g] * inv_cnt;
    const float var  = fmaf(stats[b * 64 + 2 * g + 1], inv_cnt, -mean * mean);
    const float rs   = rsqrtf(var + EPSV);
    const float sc   = gamma[o] * rs;
    const float sh   = fmaf(-mean, sc, beta[o]);

    const int HALF = NVV / 4;                   // 10240 float2 per first half
    const int c0   = half * HALF;
    const int cEnd = half ? (NVV / 2) : HALF;   // second half gets the tail (20481 total)
    float2* p = (float2*)(out + (size_t)row * NVV);
    #pragma unroll 4
    for (int c = c0 + (int)threadIdx.x; c < cEnd; c += 256) {
        float2 val = p[c];
        float y0 = fmaf(val.x, sc, sh);
        float y1 = fmaf(val.y, sc, sh);
        val.x = y0 > 0.f ? y0 : 0.f;
        val.y = y1 > 0.f ? y1 : 0.f;
        p[c] = val;
    }
}

extern "C" void kernel_launch(void* const* d_in, const int* in_sizes, int n_in,
                              void* d_out, int out_size, void* d_ws, size_t ws_size,
                              hipStream_t stream) {
    const float* x      = (const float*)d_in[0];
    const float* Lw     = (const float*)d_in[1];
    const float* Ew     = (const float*)d_in[2];
    const float* Nw     = (const float*)d_in[3];
    const float* coeffs = (const float*)d_in[4];
    const float* bias   = (const float*)d_in[5];
    const float* gamma  = (const float*)d_in[6];
    const float* beta   = (const float*)d_in[7];
    const int*   nbr    = (const int*)d_in[8];
    float* out   = (float*)d_out;
    float*          stats = (float*)d_ws;
    unsigned short* cW    = (unsigned short*)((char*)d_ws + 2048);
    float*          xT    = (float*)((char*)d_ws + 36864);   // needs ws_size >= ~21 MB

    (void)hipMemsetAsync(stats, 0, BB * 64 * sizeof(float), stream);

    k_prep<<<dim3(1), dim3(256), 0, stream>>>(coeffs, cW);

    k_tr<<<dim3(161, BB), dim3(256), 0, stream>>>(x, xT);

    k_conv<<<dim3(BB * NTILE), dim3(256), 0, stream>>>(xT, Lw, Ew, Nw, cW, bias, nbr, out, stats);

    k_norm<<<dim3(2 * BB * COUT), dim3(256), 0, stream>>>(out, stats, gamma, beta);
}

// Round 8
// 201.551 us; speedup vs baseline: 2.6022x; 1.0579x over previous
//
#include <hip/hip_runtime.h>
#include <hip/hip_bf16.h>

#define NVV    40962
#define NVP    10242
#define BB     8
#define CIN    64
#define COUT   64
#define KK     7
#define EPSV   1e-5f

#define VT      64           // vertices per tile
#define NTILE   641          // ceil(NVV/VT)
#define KDIM    256          // Cin*4
#define PSTRIDE 40968        // padded pre-GN row (bf16): 81936 B, 16B-aligned

// d_ws layout (total ~52.5 MB):
#define CW_OFF  2048         // cW bf16 coeffs [64][256]
#define XT_OFF  36864        // xT bf16 [b][v][i] : 8*10242*64*2 = 10,487,808 B
#define PRE_OFF 10524672     // pre bf16 [row][PSTRIDE] : 512*40968*2 = 41,951,232 B

typedef __attribute__((ext_vector_type(8))) short short8;
typedef __attribute__((ext_vector_type(4))) float floatx4;

__device__ __forceinline__ unsigned f2bf(float f) {
    unsigned u = __builtin_bit_cast(unsigned, f);
    return (u + 0x7FFFu + ((u >> 16) & 1u)) >> 16;    // rne (finite inputs)
}
__device__ __forceinline__ unsigned pk2(float a, float b) {   // v_cvt_pk_bf16_f32
    __hip_bfloat162 h = __float22bfloat162_rn(make_float2(a, b));
    unsigned r;
    __builtin_memcpy(&r, &h, 4);
    return r;
}
__device__ __forceinline__ float bflo(unsigned u) { return __builtin_bit_cast(float, u << 16); }
__device__ __forceinline__ float bfhi(unsigned u) { return __builtin_bit_cast(float, u & 0xffff0000u); }

// ---- transpose x -> bf16 xT[b][v][i]; block (0,0) also zeroes stats + converts coeffs ----
__global__ __launch_bounds__(256) void k_tr(const float* __restrict__ x,
                                            unsigned short* __restrict__ xT,
                                            const float* __restrict__ coeffs,
                                            unsigned short* __restrict__ cW,
                                            float* __restrict__ stats) {
    __shared__ float tile[64][65];
    const int b    = blockIdx.y;
    const int v0   = blockIdx.x * 64;
    const int lane = threadIdx.x & 63;
    const int wave = threadIdx.x >> 6;
    const int v    = v0 + lane;
    #pragma unroll
    for (int r = 0; r < 16; ++r) {
        int i = wave * 16 + r;
        tile[i][lane] = (v < NVP) ? x[((size_t)b * CIN + i) * NVP + v] : 0.f;
    }
    if (blockIdx.x == 0 && b == 0) {
        for (int t = threadIdx.x; t < 512; t += 256) stats[t] = 0.f;
        for (int t = threadIdx.x; t < COUT * KDIM; t += 256)
            cW[t] = (unsigned short)f2bf(coeffs[t]);
    }
    __syncthreads();
    const int i2 = lane & 31;
    #pragma unroll
    for (int r = 0; r < 8; ++r) {
        int vv = wave * 16 + 2 * r + (lane >> 5);
        if (v0 + vv < NVP) {
            unsigned w = pk2(tile[2 * i2][vv], tile[2 * i2 + 1][vv]);
            ((unsigned*)(xT + ((size_t)b * NVP + v0 + vv) * 64))[i2] = w;
        }
    }
}

__global__ __launch_bounds__(256, 4) void k_conv(
    const unsigned short* __restrict__ xT,
    const float* __restrict__ Lw,
    const float* __restrict__ Ew,
    const float* __restrict__ Nw,
    const unsigned short* __restrict__ cW,
    const float* __restrict__ bias,
    const int*   __restrict__ nbr,
    unsigned short* __restrict__ pre,
    float* __restrict__ stats)
{
    // F: 64 rows x 256 bf16 (512 B/row), XOR-swizzled in 16B groups (conflict-free)
    __shared__ unsigned short Fbuf[VT * 256];       // 32 KB; reused as float outT[64][68]
    __shared__ float sred[4][4][4];

    const int bid   = blockIdx.x;
    const int b     = bid & 7;                // b <-> XCD affinity: xT[b] slab L2-resident
    const int tile  = bid >> 3;
    const int vbase = tile * VT;
    const int tid   = threadIdx.x;
    const int wave  = tid >> 6;
    const int lane  = tid & 63;
    const int q     = lane >> 4;
    const int l15   = lane & 15;

    // ---- Stage A: thread (v=lane, ch-chunk = wave*16..+16); deep gather prefetch ----
    {
        const int v  = lane;
        const int ic = wave;
        const int vg = vbase + v;
        const bool va = (vg < NVV);
        int jj[KK]; float wl[KK], we[KK], wn[KK];
        #pragma unroll
        for (int k = 0; k < KK; ++k) { jj[k] = NVP; wl[k] = we[k] = wn[k] = 0.f; }
        if (va) {
            #pragma unroll
            for (int k = 0; k < KK; ++k) {
                jj[k] = nbr[vg * KK + k];
                wl[k] = Lw[vg * KK + k];
                we[k] = Ew[vg * KK + k];
                wn[k] = Nw[vg * KK + k];
            }
        }
        const unsigned short* xTb = xT + (size_t)b * NVP * 64 + ic * 16;

        uint4 ga[KK], gb[KK], gu0, gu1;
        gu0 = gu1 = make_uint4(0, 0, 0, 0);
        #pragma unroll
        for (int k = 0; k < KK; ++k) { ga[k] = make_uint4(0,0,0,0); gb[k] = make_uint4(0,0,0,0); }
        if (vg < NVP) {
            const uint4* p = (const uint4*)(xTb + (size_t)vg * 64);
            gu0 = p[0]; gu1 = p[1];
        }
        #pragma unroll
        for (int k = 0; k < KK; ++k) {          // all 7 gathers issued before any use
            if (jj[k] < NVP) {
                const uint4* p = (const uint4*)(xTb + (size_t)jj[k] * 64);
                ga[k] = p[0]; gb[k] = p[1];
            }
        }

        float l[16], e[16], n[16];
        #pragma unroll
        for (int t = 0; t < 16; ++t) { l[t] = e[t] = n[t] = 0.f; }
        #pragma unroll
        for (int k = 0; k < KK; ++k) {
            const float a = wl[k], bb2 = we[k], c2 = wn[k];
            const unsigned uu[8] = { ga[k].x, ga[k].y, ga[k].z, ga[k].w,
                                     gb[k].x, gb[k].y, gb[k].z, gb[k].w };
            #pragma unroll
            for (int j2 = 0; j2 < 8; ++j2) {
                float f0 = bflo(uu[j2]), f1 = bfhi(uu[j2]);   // zeros contribute 0
                l[2*j2]   = fmaf(f0, a,  l[2*j2]);   e[2*j2]   = fmaf(f0, bb2, e[2*j2]);   n[2*j2]   = fmaf(f0, c2, n[2*j2]);
                l[2*j2+1] = fmaf(f1, a,  l[2*j2+1]); e[2*j2+1] = fmaf(f1, bb2, e[2*j2+1]); n[2*j2+1] = fmaf(f1, c2, n[2*j2+1]);
            }
        }
        // pack into F: group g holds k=8g..8g+7 = ch-pair {2g,2g+1} x {u,l,e,n}
        const unsigned uup[8] = { gu0.x, gu0.y, gu0.z, gu0.w, gu1.x, gu1.y, gu1.z, gu1.w };
        #pragma unroll
        for (int jg = 0; jg < 8; ++jg) {
            const int i0 = 2 * jg;
            uint4 w;
            w.x = pk2(bflo(uup[jg]), l[i0]);        // u bf16 passthrough is exact
            w.y = pk2(e[i0],   n[i0]);
            w.z = pk2(bfhi(uup[jg]) , l[i0+1]);
            w.w = pk2(e[i0+1], n[i0+1]);
            const int g    = ic * 8 + jg;
            const int phys = g ^ (v & 31);
            *(uint4*)(Fbuf + v * 256 + phys * 8) = w;
        }
    }
    __syncthreads();

    // ---- W fragments (A-operand): lane holds A[m=l15][k=32*k0+8*q+j]; direct bf16 load ----
    short8 afrag[8];
    {
        const unsigned short* wrow = cW + (16 * wave + l15) * KDIM + q * 8;
        #pragma unroll
        for (int k0 = 0; k0 < 8; ++k0)
            afrag[k0] = *(const short8*)(wrow + k0 * 32);
    }

    // ---- MFMA: B[n=l15][k] from swizzled F ----
    floatx4 acc[4] = {{0,0,0,0},{0,0,0,0},{0,0,0,0},{0,0,0,0}};
    #pragma unroll
    for (int k0 = 0; k0 < 8; ++k0) {
        #pragma unroll
        for (int nt = 0; nt < 4; ++nt) {
            const int row  = nt * 16 + l15;
            const int phys = (k0 * 4 + q) ^ (row & 31);
            const short8 bfrag = *(const short8*)(Fbuf + row * 256 + phys * 8);
            acc[nt] = __builtin_amdgcn_mfma_f32_16x16x32_bf16(afrag[k0], bfrag, acc[nt], 0, 0, 0);
        }
    }

    // ---- Epilogue: bias, GN partial stats, bf16 pre-GN stores via LDS transpose ----
    float bs[4];
    #pragma unroll
    for (int r = 0; r < 4; ++r) bs[r] = bias[16 * wave + q * 4 + r];

    float cv[4][4];
    float sA = 0.f, s2A = 0.f, sB = 0.f, s2B = 0.f;
    #pragma unroll
    for (int nt = 0; nt < 4; ++nt) {
        const bool ok = (vbase + nt * 16 + l15 < NVV);
        #pragma unroll
        for (int r = 0; r < 4; ++r) {
            float c = acc[nt][r] + bs[r];
            cv[nt][r] = c;
            if (ok) {
                if (r < 2) { sA += c; s2A = fmaf(c, c, s2A); }
                else       { sB += c; s2B = fmaf(c, c, s2B); }
            }
        }
    }
    #pragma unroll
    for (int m = 1; m < 16; m <<= 1) {
        sA  += __shfl_xor(sA,  m);
        s2A += __shfl_xor(s2A, m);
        sB  += __shfl_xor(sB,  m);
        s2B += __shfl_xor(s2B, m);
    }
    if (l15 == 0) {
        sred[wave][q][0] = sA; sred[wave][q][1] = s2A;
        sred[wave][q][2] = sB; sred[wave][q][3] = s2B;
    }
    __syncthreads();                 // F reads done; reuse Fbuf as outT

    float* outT = (float*)Fbuf;      // [64 o][stride 68]
    #pragma unroll
    for (int nt = 0; nt < 4; ++nt)
        #pragma unroll
        for (int r = 0; r < 4; ++r)
            outT[(16 * wave + 4 * q + r) * 68 + nt * 16 + l15] = cv[nt][r];
    __syncthreads();

    if (lane < 32) {                 // bf16-pair stores: 128 B contiguous per oo-row
        const int vloc = 2 * lane;
        if (vbase + vloc < NVV) {    // pair {v, v+1}: second lands in row pad if == NVV
            unsigned short* prow = pre + (size_t)(b * COUT + 16 * wave) * PSTRIDE + vbase;
            #pragma unroll
            for (int oo = 0; oo < 16; ++oo) {
                float2 t = *(const float2*)(outT + (16 * wave + oo) * 68 + vloc);
                *(unsigned*)(prow + (size_t)oo * PSTRIDE + vloc) = pk2(t.x, t.y);
            }
        }
    }

    if (tid < 64) {
        const int w = tid >> 4, qq = (tid >> 2) & 3, e = tid & 3;
        const int g = 8 * w + 2 * qq + (e >> 1);
        atomicAdd(&stats[b * 64 + 2 * g + (e & 1)], sred[w][qq][e]);
    }
}

// grid: 2048 blocks = 4 per row; split-stream: read bf16 pre, write f32 out.
__global__ __launch_bounds__(256) void k_norm(
    const unsigned short* __restrict__ pre,
    float* __restrict__ out,
    const float* __restrict__ stats,
    const float* __restrict__ gamma,
    const float* __restrict__ beta)
{
    const int row     = blockIdx.x >> 2;        // b*64 + o
    const int quarter = blockIdx.x & 3;
    const int o = row & (COUT - 1);
    const int b = row >> 6;
    const int g = o >> 1;
    const float inv_cnt = 1.f / (float)(2 * NVV);
    const float mean = stats[b * 64 + 2 * g] * inv_cnt;
    const float var  = fmaf(stats[b * 64 + 2 * g + 1], inv_cnt, -mean * mean);
    const float rs   = rsqrtf(var + EPSV);
    const float sc   = gamma[o] * rs;
    const float sh   = fmaf(-mean, sc, beta[o]);

    const uint4* src = (const uint4*)(pre + (size_t)row * PSTRIDE);
    float* orow = out + (size_t)row * NVV;
    #pragma unroll
    for (int it = 0; it < 5; ++it) {            // 4 quarters x 5 x 256 = 5120 uint4 = v<40960
        const int c = quarter * 1280 + it * 256 + (int)threadIdx.x;
        uint4 u = src[c];
        float f[8] = { bflo(u.x), bfhi(u.x), bflo(u.y), bfhi(u.y),
                       bflo(u.z), bfhi(u.z), bflo(u.w), bfhi(u.w) };
        float* p = orow + 8 * c;
        #pragma unroll
        for (int t = 0; t < 4; ++t) {
            float y0 = fmaf(f[2*t],   sc, sh);
            float y1 = fmaf(f[2*t+1], sc, sh);
            float2 v2 = make_float2(y0 > 0.f ? y0 : 0.f, y1 > 0.f ? y1 : 0.f);
            *(float2*)(p + 2 * t) = v2;         // 8B-aligned: row base %8==0, offset even
        }
    }
    if (quarter == 3 && threadIdx.x == 0) {     // tail v = 40960, 40961
        unsigned u = *(const unsigned*)(pre + (size_t)row * PSTRIDE + 40960);
        float y0 = fmaf(bflo(u), sc, sh);
        float y1 = fmaf(bfhi(u), sc, sh);
        *(float2*)(orow + 40960) = make_float2(y0 > 0.f ? y0 : 0.f, y1 > 0.f ? y1 : 0.f);
    }
}

extern "C" void kernel_launch(void* const* d_in, const int* in_sizes, int n_in,
                              void* d_out, int out_size, void* d_ws, size_t ws_size,
                              hipStream_t stream) {
    const float* x      = (const float*)d_in[0];
    const float* Lw     = (const float*)d_in[1];
    const float* Ew     = (const float*)d_in[2];
    const float* Nw     = (const float*)d_in[3];
    const float* coeffs = (const float*)d_in[4];
    const float* bias   = (const float*)d_in[5];
    const float* gamma  = (const float*)d_in[6];
    const float* beta   = (const float*)d_in[7];
    const int*   nbr    = (const int*)d_in[8];
    float* out = (float*)d_out;
    float*          stats = (float*)d_ws;
    unsigned short* cW    = (unsigned short*)((char*)d_ws + CW_OFF);
    unsigned short* xT    = (unsigned short*)((char*)d_ws + XT_OFF);
    unsigned short* pre   = (unsigned short*)((char*)d_ws + PRE_OFF);  // needs ws >= ~53 MB

    k_tr<<<dim3(161, BB), dim3(256), 0, stream>>>(x, xT, coeffs, cW, stats);

    k_conv<<<dim3(BB * NTILE), dim3(256), 0, stream>>>(xT, Lw, Ew, Nw, cW, bias, nbr, pre, stats);

    k_norm<<<dim3(4 * BB * COUT), dim3(256), 0, stream>>>(pre, out, stats, gamma, beta);
}

// Round 9
// 198.841 us; speedup vs baseline: 2.6376x; 1.0136x over previous
//
#include <hip/hip_runtime.h>
#include <hip/hip_bf16.h>

#define NVV    40962
#define NVP    10242
#define BB     8
#define CIN    64
#define COUT   64
#define KK     7
#define EPSV   1e-5f

#define VT      64           // vertices per tile
#define NTILE   641          // ceil(NVV/VT)
#define KDIM    256          // Cin*4
#define PSTRIDE 41024        // padded pre-GN row (bf16): 82048 B = 641 x 128 B  (line-aligned!)

// d_ws layout (total ~52.6 MB):
#define CW_OFF  2048         // cW bf16 coeffs [64][256]
#define XT_OFF  36864        // xT bf16 [b][v][i] : 8*10242*64*2 = 10,487,808 B
#define PRE_OFF 10524672     // pre bf16 [row][PSTRIDE] : 512*41024*2 = 42,008,576 B (128B-aligned)

typedef __attribute__((ext_vector_type(8))) short short8;
typedef __attribute__((ext_vector_type(4))) float floatx4;

__device__ __forceinline__ unsigned f2bf(float f) {
    unsigned u = __builtin_bit_cast(unsigned, f);
    return (u + 0x7FFFu + ((u >> 16) & 1u)) >> 16;    // rne (finite inputs)
}
__device__ __forceinline__ unsigned pk2(float a, float b) {   // v_cvt_pk_bf16_f32
    __hip_bfloat162 h = __float22bfloat162_rn(make_float2(a, b));
    unsigned r;
    __builtin_memcpy(&r, &h, 4);
    return r;
}
__device__ __forceinline__ float bflo(unsigned u) { return __builtin_bit_cast(float, u << 16); }
__device__ __forceinline__ float bfhi(unsigned u) { return __builtin_bit_cast(float, u & 0xffff0000u); }

// ---- transpose x -> bf16 xT[b][v][i]; block (0,0) also zeroes stats + converts coeffs ----
__global__ __launch_bounds__(256) void k_tr(const float* __restrict__ x,
                                            unsigned short* __restrict__ xT,
                                            const float* __restrict__ coeffs,
                                            unsigned short* __restrict__ cW,
                                            float* __restrict__ stats) {
    __shared__ float tile[64][65];
    const int b    = blockIdx.y;
    const int v0   = blockIdx.x * 64;
    const int lane = threadIdx.x & 63;
    const int wave = threadIdx.x >> 6;
    const int v    = v0 + lane;
    #pragma unroll
    for (int r = 0; r < 16; ++r) {
        int i = wave * 16 + r;
        tile[i][lane] = (v < NVP) ? x[((size_t)b * CIN + i) * NVP + v] : 0.f;
    }
    if (blockIdx.x == 0 && b == 0) {
        for (int t = threadIdx.x; t < 512; t += 256) stats[t] = 0.f;
        for (int t = threadIdx.x; t < COUT * KDIM; t += 256)
            cW[t] = (unsigned short)f2bf(coeffs[t]);
    }
    __syncthreads();
    const int i2 = lane & 31;
    #pragma unroll
    for (int r = 0; r < 8; ++r) {
        int vv = wave * 16 + 2 * r + (lane >> 5);
        if (v0 + vv < NVP) {
            unsigned w = pk2(tile[2 * i2][vv], tile[2 * i2 + 1][vv]);
            ((unsigned*)(xT + ((size_t)b * NVP + v0 + vv) * 64))[i2] = w;
        }
    }
}

__global__ __launch_bounds__(256, 4) void k_conv(
    const unsigned short* __restrict__ xT,
    const float* __restrict__ Lw,
    const float* __restrict__ Ew,
    const float* __restrict__ Nw,
    const unsigned short* __restrict__ cW,
    const float* __restrict__ bias,
    const int*   __restrict__ nbr,
    unsigned short* __restrict__ pre,
    float* __restrict__ stats)
{
    // F: 64 rows x 256 bf16 (512 B/row), XOR-swizzled in 16B groups (conflict-free)
    __shared__ unsigned short Fbuf[VT * 256];       // 32 KB; reused as float outT[64][68]
    __shared__ float sred[4][4][4];

    const int bid   = blockIdx.x;
    const int b     = bid & 7;                // b <-> XCD affinity: xT[b] slab L2-resident
    const int tile  = bid >> 3;
    const int vbase = tile * VT;
    const int tid   = threadIdx.x;
    const int wave  = tid >> 6;
    const int lane  = tid & 63;
    const int q     = lane >> 4;
    const int l15   = lane & 15;

    // ---- Stage A: thread (v=lane, ch-chunk = wave*16..+16); deep gather prefetch ----
    {
        const int v  = lane;
        const int ic = wave;
        const int vg = vbase + v;
        const bool va = (vg < NVV);
        int jj[KK]; float wl[KK], we[KK], wn[KK];
        #pragma unroll
        for (int k = 0; k < KK; ++k) { jj[k] = NVP; wl[k] = we[k] = wn[k] = 0.f; }
        if (va) {
            #pragma unroll
            for (int k = 0; k < KK; ++k) {
                jj[k] = nbr[vg * KK + k];
                wl[k] = Lw[vg * KK + k];
                we[k] = Ew[vg * KK + k];
                wn[k] = Nw[vg * KK + k];
            }
        }
        const unsigned short* xTb = xT + (size_t)b * NVP * 64 + ic * 16;

        uint4 ga[KK], gb[KK], gu0, gu1;
        gu0 = gu1 = make_uint4(0, 0, 0, 0);
        #pragma unroll
        for (int k = 0; k < KK; ++k) { ga[k] = make_uint4(0,0,0,0); gb[k] = make_uint4(0,0,0,0); }
        if (vg < NVP) {
            const uint4* p = (const uint4*)(xTb + (size_t)vg * 64);
            gu0 = p[0]; gu1 = p[1];
        }
        #pragma unroll
        for (int k = 0; k < KK; ++k) {          // all 7 gathers issued before any use
            if (jj[k] < NVP) {
                const uint4* p = (const uint4*)(xTb + (size_t)jj[k] * 64);
                ga[k] = p[0]; gb[k] = p[1];
            }
        }

        float l[16], e[16], n[16];
        #pragma unroll
        for (int t = 0; t < 16; ++t) { l[t] = e[t] = n[t] = 0.f; }
        #pragma unroll
        for (int k = 0; k < KK; ++k) {
            const float a = wl[k], bb2 = we[k], c2 = wn[k];
            const unsigned uu[8] = { ga[k].x, ga[k].y, ga[k].z, ga[k].w,
                                     gb[k].x, gb[k].y, gb[k].z, gb[k].w };
            #pragma unroll
            for (int j2 = 0; j2 < 8; ++j2) {
                float f0 = bflo(uu[j2]), f1 = bfhi(uu[j2]);   // zeros contribute 0
                l[2*j2]   = fmaf(f0, a,  l[2*j2]);   e[2*j2]   = fmaf(f0, bb2, e[2*j2]);   n[2*j2]   = fmaf(f0, c2, n[2*j2]);
                l[2*j2+1] = fmaf(f1, a,  l[2*j2+1]); e[2*j2+1] = fmaf(f1, bb2, e[2*j2+1]); n[2*j2+1] = fmaf(f1, c2, n[2*j2+1]);
            }
        }
        // pack into F: group g holds k=8g..8g+7 = ch-pair {2g,2g+1} x {u,l,e,n}
        const unsigned uup[8] = { gu0.x, gu0.y, gu0.z, gu0.w, gu1.x, gu1.y, gu1.z, gu1.w };
        #pragma unroll
        for (int jg = 0; jg < 8; ++jg) {
            const int i0 = 2 * jg;
            uint4 w;
            w.x = pk2(bflo(uup[jg]), l[i0]);        // u bf16 passthrough is exact
            w.y = pk2(e[i0],   n[i0]);
            w.z = pk2(bfhi(uup[jg]) , l[i0+1]);
            w.w = pk2(e[i0+1], n[i0+1]);
            const int g    = ic * 8 + jg;
            const int phys = g ^ (v & 31);
            *(uint4*)(Fbuf + v * 256 + phys * 8) = w;
        }
    }
    __syncthreads();

    // ---- W fragments (A-operand): lane holds A[m=l15][k=32*k0+8*q+j]; direct bf16 load ----
    short8 afrag[8];
    {
        const unsigned short* wrow = cW + (16 * wave + l15) * KDIM + q * 8;
        #pragma unroll
        for (int k0 = 0; k0 < 8; ++k0)
            afrag[k0] = *(const short8*)(wrow + k0 * 32);
    }

    // ---- MFMA: B[n=l15][k] from swizzled F ----
    floatx4 acc[4] = {{0,0,0,0},{0,0,0,0},{0,0,0,0},{0,0,0,0}};
    #pragma unroll
    for (int k0 = 0; k0 < 8; ++k0) {
        #pragma unroll
        for (int nt = 0; nt < 4; ++nt) {
            const int row  = nt * 16 + l15;
            const int phys = (k0 * 4 + q) ^ (row & 31);
            const short8 bfrag = *(const short8*)(Fbuf + row * 256 + phys * 8);
            acc[nt] = __builtin_amdgcn_mfma_f32_16x16x32_bf16(afrag[k0], bfrag, acc[nt], 0, 0, 0);
        }
    }

    // ---- Epilogue: bias, GN partial stats, bf16 pre-GN stores via LDS transpose ----
    float bs[4];
    #pragma unroll
    for (int r = 0; r < 4; ++r) bs[r] = bias[16 * wave + q * 4 + r];

    float cv[4][4];
    float sA = 0.f, s2A = 0.f, sB = 0.f, s2B = 0.f;
    #pragma unroll
    for (int nt = 0; nt < 4; ++nt) {
        const bool ok = (vbase + nt * 16 + l15 < NVV);
        #pragma unroll
        for (int r = 0; r < 4; ++r) {
            float c = acc[nt][r] + bs[r];
            cv[nt][r] = c;
            if (ok) {
                if (r < 2) { sA += c; s2A = fmaf(c, c, s2A); }
                else       { sB += c; s2B = fmaf(c, c, s2B); }
            }
        }
    }
    #pragma unroll
    for (int m = 1; m < 16; m <<= 1) {
        sA  += __shfl_xor(sA,  m);
        s2A += __shfl_xor(s2A, m);
        sB  += __shfl_xor(sB,  m);
        s2B += __shfl_xor(s2B, m);
    }
    if (l15 == 0) {
        sred[wave][q][0] = sA; sred[wave][q][1] = s2A;
        sred[wave][q][2] = sB; sred[wave][q][3] = s2B;
    }
    __syncthreads();                 // F reads done; reuse Fbuf as outT

    float* outT = (float*)Fbuf;      // [64 o][stride 68]
    #pragma unroll
    for (int nt = 0; nt < 4; ++nt)
        #pragma unroll
        for (int r = 0; r < 4; ++r)
            outT[(16 * wave + 4 * q + r) * 68 + nt * 16 + l15] = cv[nt][r];
    __syncthreads();

    {   // all 64 lanes: (oo-half = lane>>5, vpair = lane&31); 2 rows x 128 B per iter
        const int oo2  = lane >> 5;
        const int vloc = 2 * (lane & 31);
        if (vbase + vloc < NVV) {    // pair {v,v+1}: both valid or both OOB (NVV even)
            unsigned short* prow = pre + (size_t)(b * COUT + 16 * wave) * PSTRIDE + vbase;
            #pragma unroll
            for (int ot = 0; ot < 8; ++ot) {
                const int oo = 2 * ot + oo2;
                float2 t = *(const float2*)(outT + (16 * wave + oo) * 68 + vloc);
                *(unsigned*)(prow + (size_t)oo * PSTRIDE + vloc) = pk2(t.x, t.y);
            }
        }
    }

    if (tid < 64) {
        const int w = tid >> 4, qq = (tid >> 2) & 3, e = tid & 3;
        const int g = 8 * w + 2 * qq + (e >> 1);
        atomicAdd(&stats[b * 64 + 2 * g + (e & 1)], sred[w][qq][e]);
    }
}

// grid: 2048 blocks; blk = b + 8*(o + 64*quarter) -> blk%8==b matches k_conv's
// writer XCD (pre[b] rows live in XCD b's L2). Split-stream: read bf16 pre, write f32 out.
__global__ __launch_bounds__(256) void k_norm(
    const unsigned short* __restrict__ pre,
    float* __restrict__ out,
    const float* __restrict__ stats,
    const float* __restrict__ gamma,
    const float* __restrict__ beta)
{
    const int blk     = blockIdx.x;
    const int b       = blk & 7;
    const int rest    = blk >> 3;               // 0..255
    const int o       = rest & 63;
    const int quarter = rest >> 6;
    const int row     = b * 64 + o;
    const int g = o >> 1;
    const float inv_cnt = 1.f / (float)(2 * NVV);
    const float mean = stats[b * 64 + 2 * g] * inv_cnt;
    const float var  = fmaf(stats[b * 64 + 2 * g + 1], inv_cnt, -mean * mean);
    const float rs   = rsqrtf(var + EPSV);
    const float sc   = gamma[o] * rs;
    const float sh   = fmaf(-mean, sc, beta[o]);

    const uint4* src = (const uint4*)(pre + (size_t)row * PSTRIDE);
    float* orow = out + (size_t)row * NVV;
    #pragma unroll
    for (int it = 0; it < 5; ++it) {            // 4 quarters x 5 x 256 = 5120 uint4 = v<40960
        const int c = quarter * 1280 + it * 256 + (int)threadIdx.x;
        uint4 u = src[c];
        float f[8] = { bflo(u.x), bfhi(u.x), bflo(u.y), bfhi(u.y),
                       bflo(u.z), bfhi(u.z), bflo(u.w), bfhi(u.w) };
        float* p = orow + 8 * c;
        #pragma unroll
        for (int t = 0; t < 4; ++t) {
            float y0 = fmaf(f[2*t],   sc, sh);
            float y1 = fmaf(f[2*t+1], sc, sh);
            float2 v2 = make_float2(y0 > 0.f ? y0 : 0.f, y1 > 0.f ? y1 : 0.f);
            *(float2*)(p + 2 * t) = v2;         // 8B-aligned always
        }
    }
    if (quarter == 3 && threadIdx.x == 0) {     // tail v = 40960, 40961
        unsigned u = *(const unsigned*)(pre + (size_t)row * PSTRIDE + 40960);
        float y0 = fmaf(bflo(u), sc, sh);
        float y1 = fmaf(bfhi(u), sc, sh);
        *(float2*)(orow + 40960) = make_float2(y0 > 0.f ? y0 : 0.f, y1 > 0.f ? y1 : 0.f);
    }
}

extern "C" void kernel_launch(void* const* d_in, const int* in_sizes, int n_in,
                              void* d_out, int out_size, void* d_ws, size_t ws_size,
                              hipStream_t stream) {
    const float* x      = (const float*)d_in[0];
    const float* Lw     = (const float*)d_in[1];
    const float* Ew     = (const float*)d_in[2];
    const float* Nw     = (const float*)d_in[3];
    const float* coeffs = (const float*)d_in[4];
    const float* bias   = (const float*)d_in[5];
    const float* gamma  = (const float*)d_in[6];
    const float* beta   = (const float*)d_in[7];
    const int*   nbr    = (const int*)d_in[8];
    float* out = (float*)d_out;
    float*          stats = (float*)d_ws;
    unsigned short* cW    = (unsigned short*)((char*)d_ws + CW_OFF);
    unsigned short* xT    = (unsigned short*)((char*)d_ws + XT_OFF);
    unsigned short* pre   = (unsigned short*)((char*)d_ws + PRE_OFF);  // needs ws >= ~53 MB

    k_tr<<<dim3(161, BB), dim3(256), 0, stream>>>(x, xT, coeffs, cW, stats);

    k_conv<<<dim3(BB * NTILE), dim3(256), 0, stream>>>(xT, Lw, Ew, Nw, cW, bias, nbr, pre, stats);

    k_norm<<<dim3(4 * BB * COUT), dim3(256), 0, stream>>>(pre, out, stats, gamma, beta);
}